// Round 2
// baseline (2753.016 us; speedup 1.0000x reference)
//
#include <hip/hip_runtime.h>
#include <hip/hip_bf16.h>

// Problem constants (B,N,D,H = 4,2048,512,8; DK=64)
// Dataset dtype: fp32 inputs / fp32 output (threshold 1.3 = 2% of max|ref|=65;
// bf16 misread produced NaN in R1). Intermediates bf16 in ws (33.5 MB, proven fit).
#define B_  4
#define N_  2048
#define D_  512
#define H_  8
#define DK_ 64

typedef unsigned short u16;
typedef __attribute__((ext_vector_type(8))) unsigned short ushort8;
typedef __attribute__((ext_vector_type(4))) float float4v;

__device__ __forceinline__ float bf2f(u16 u) {
    union { unsigned int i; float f; } v;
    v.i = ((unsigned int)u) << 16;
    return v.f;
}
__device__ __forceinline__ u16 f2bf(float f) {
    union { float f; unsigned int i; } v;
    v.f = f;
    unsigned int r = v.i + 0x7FFFu + ((v.i >> 16) & 1u);  // round-to-nearest-even
    return (u16)(r >> 16);
}

// ---------------------------------------------------------------------------
// C[M,512] = X[M,512] @ W[512,512]^T(fp32) + bias(fp32)
// IN_BF16: X is bf16 (ws) else fp32 (d_in). OUT_BF16: C is bf16 (ws) else fp32.
// 128x128 tile, 256 threads, 8x8 micro-tile, BK=32.
// grid = (512/128, M/128, nmat); z selects X0/X1/X2, output offset z*M*512.
// ---------------------------------------------------------------------------
template <bool IN_BF16, bool OUT_BF16>
__global__ __launch_bounds__(256) void proj_gemm(
    const void* __restrict__ X0v, const void* __restrict__ X1v,
    const void* __restrict__ X2v, const float* __restrict__ W,
    const float* __restrict__ bias, void* __restrict__ C0v, int M)
{
    __shared__ float As[32][132];   // [k][m], pad 132 (528B rows, 16B aligned)
    __shared__ float Ws[32][132];   // [k][e]

    const int t = threadIdx.x;
    const int z = blockIdx.z;
    const void* Xv = (z == 0) ? X0v : ((z == 1) ? X1v : X2v);

    const int e0 = blockIdx.x * 128;
    const int m0 = blockIdx.y * 128;
    const int tr = t >> 4;     // 0..15 -> rows tr*8..tr*8+7
    const int tc = t & 15;     // 0..15 -> cols tc*8..tc*8+7

    float acc[8][8] = {};

    for (int k0 = 0; k0 < 512; k0 += 32) {
        // ---- stage X tile: 128 rows x 32 k -> As[k][row] (fp32) ----
        if (IN_BF16) {
            const u16* X = (const u16*)Xv;
            #pragma unroll
            for (int i = 0; i < 2; ++i) {
                int v    = t + 256 * i;          // 0..511
                int row  = v >> 2;               // 0..127
                int col8 = (v & 3) * 8;          // 0,8,16,24
                ushort8 ua = *(const ushort8*)(X + (size_t)(m0 + row) * 512 + k0 + col8);
                #pragma unroll
                for (int j = 0; j < 8; ++j) As[col8 + j][row] = bf2f(ua[j]);
            }
        } else {
            const float* X = (const float*)Xv;
            #pragma unroll
            for (int i = 0; i < 4; ++i) {
                int v   = t + 256 * i;           // 0..1023
                int row = v >> 3;                // 0..127
                int c4  = (v & 7) * 4;           // 0..28
                float4v x = *(const float4v*)(X + (size_t)(m0 + row) * 512 + k0 + c4);
                #pragma unroll
                for (int j = 0; j < 4; ++j) As[c4 + j][row] = x[j];
            }
        }
        // ---- stage W tile (always fp32): 128 rows x 32 k -> Ws[k][row] ----
        #pragma unroll
        for (int i = 0; i < 4; ++i) {
            int v   = t + 256 * i;
            int row = v >> 3;
            int c4  = (v & 7) * 4;
            float4v w = *(const float4v*)(W + (size_t)(e0 + row) * 512 + k0 + c4);
            #pragma unroll
            for (int j = 0; j < 4; ++j) Ws[c4 + j][row] = w[j];
        }
        __syncthreads();

        #pragma unroll 8
        for (int kk = 0; kk < 32; ++kk) {
            float4v a0 = *(const float4v*)&As[kk][tr * 8];
            float4v a1 = *(const float4v*)&As[kk][tr * 8 + 4];
            float4v b0 = *(const float4v*)&Ws[kk][tc * 8];
            float4v b1 = *(const float4v*)&Ws[kk][tc * 8 + 4];
            #pragma unroll
            for (int i = 0; i < 8; ++i) {
                float av = (i < 4) ? a0[i] : a1[i - 4];
                #pragma unroll
                for (int j = 0; j < 8; ++j) {
                    float bv = (j < 4) ? b0[j] : b1[j - 4];
                    acc[i][j] += av * bv;
                }
            }
        }
        __syncthreads();
    }

    // ---- epilogue: + bias (fp32) ----
    if (OUT_BF16) {
        u16* C = (u16*)C0v + (size_t)z * (size_t)M * D_;
        #pragma unroll
        for (int i = 0; i < 8; ++i) {
            ushort8 o;
            #pragma unroll
            for (int j = 0; j < 8; ++j)
                o[j] = f2bf(acc[i][j] + bias[e0 + tc * 8 + j]);
            *(ushort8*)(C + (size_t)(m0 + tr * 8 + i) * 512 + e0 + tc * 8) = o;
        }
    } else {
        float* C = (float*)C0v + (size_t)z * (size_t)M * D_;
        #pragma unroll
        for (int i = 0; i < 8; ++i) {
            float4v o0, o1;
            #pragma unroll
            for (int j = 0; j < 4; ++j) {
                o0[j] = acc[i][j]     + bias[e0 + tc * 8 + j];
                o1[j] = acc[i][j + 4] + bias[e0 + tc * 8 + 4 + j];
            }
            float* cp = C + (size_t)(m0 + tr * 8 + i) * 512 + e0 + tc * 8;
            *(float4v*)cp       = o0;
            *(float4v*)(cp + 4) = o1;
        }
    }
}

// ---------------------------------------------------------------------------
// Fused attention with softmax over the HEADS axis (reference's axis=1 bug).
// For each (b,n,m): s_h = (1/8) * dot64(Qp[n, h*64:], Kp[m, h*64:]),
// p_h = softmax_h(s_h);  A[n, h*64+d] += p_h * Vp[m, h*64+d].
// No normalization over m -> free m-tiling, no online softmax.
// Block: 16 query rows x full D=512. grid = (N/16, B). 256 threads. bf16 in/out.
// ---------------------------------------------------------------------------
__global__ __launch_bounds__(256) void attn_fused(
    const u16* __restrict__ Qp, const u16* __restrict__ Kp,
    const u16* __restrict__ Vp, u16* __restrict__ A)
{
    __shared__ float Ks[16][516];   // fp32 K tile, 33.0 KB
    __shared__ u16   Vs[16][520];   // bf16 V tile, 16.25 KB
    __shared__ float Ps[16][16][9]; // scores->probs, 9.0 KB

    const int t  = threadIdx.x;
    const int b  = blockIdx.y;
    const int n0 = blockIdx.x * 16;

    // score-phase role: (row r, head h, m-half g)
    const int r = t >> 4;          // 0..15
    const int h = (t >> 1) & 7;    // 0..7
    const int g = t & 1;           // 0..1
    // AV-phase role: (row r2, 32-col slab c0)
    const int r2 = t >> 4;
    const int c0 = (t & 15) * 32;  // 0..480, stays inside one head
    const int h2 = c0 >> 6;

    // q fragment: 64-wide head slice of row n0+r, head h (in VGPRs all kernel)
    float q[64];
    {
        const u16* qp = Qp + ((size_t)(b * N_ + n0 + r) * D_ + h * 64);
        #pragma unroll
        for (int v8 = 0; v8 < 8; ++v8) {
            ushort8 u = *(const ushort8*)(qp + v8 * 8);
            #pragma unroll
            for (int j = 0; j < 8; ++j) q[v8 * 8 + j] = bf2f(u[j]);
        }
    }

    float acc[32] = {};

    for (int m0 = 0; m0 < N_; m0 += 16) {
        // ---- stage K (fp32) and V (bf16) tiles: 16 rows x 512 ----
        #pragma unroll
        for (int i = 0; i < 4; ++i) {
            int v    = t + 256 * i;        // 0..1023
            int row  = v >> 6;             // 0..15
            int col8 = (v & 63) * 8;       // 0..504
            const size_t gidx = (size_t)(b * N_ + m0 + row) * D_ + col8;
            ushort8 uk = *(const ushort8*)(Kp + gidx);
            #pragma unroll
            for (int j = 0; j < 8; ++j) Ks[row][col8 + j] = bf2f(uk[j]);
            *(ushort8*)&Vs[row][col8] = *(const ushort8*)(Vp + gidx);
        }
        __syncthreads();

        // ---- scores: each thread -> 8 m's for its (r,h) ----
        #pragma unroll 2
        for (int mmq = 0; mmq < 8; ++mmq) {
            int mm = g * 8 + mmq;
            const float* kr = &Ks[mm][h * 64];
            float s = 0.f;
            #pragma unroll
            for (int j4 = 0; j4 < 16; ++j4) {
                float4v k4 = *(const float4v*)(kr + j4 * 4);
                s += q[j4 * 4 + 0] * k4[0] + q[j4 * 4 + 1] * k4[1]
                   + q[j4 * 4 + 2] * k4[2] + q[j4 * 4 + 3] * k4[3];
            }
            Ps[r][mm][h] = s * 0.125f;     // 1/sqrt(DK)=1/8
        }
        __syncthreads();

        // ---- softmax over the 8 heads, one (n,m) pair per thread ----
        {
            int rr = t >> 4, cc = t & 15;
            float sv[8];
            #pragma unroll
            for (int i = 0; i < 8; ++i) sv[i] = Ps[rr][cc][i];
            float mx = sv[0];
            #pragma unroll
            for (int i = 1; i < 8; ++i) mx = fmaxf(mx, sv[i]);
            float sum = 0.f;
            #pragma unroll
            for (int i = 0; i < 8; ++i) { sv[i] = __expf(sv[i] - mx); sum += sv[i]; }
            float inv = 1.f / sum;
            #pragma unroll
            for (int i = 0; i < 8; ++i) Ps[rr][cc][i] = sv[i] * inv;
        }
        __syncthreads();

        // ---- A += P * V : thread owns row r2, cols c0..c0+31 ----
        #pragma unroll 4
        for (int mm = 0; mm < 16; ++mm) {
            float p = Ps[r2][mm][h2];
            #pragma unroll
            for (int v8 = 0; v8 < 4; ++v8) {
                ushort8 u = *(const ushort8*)&Vs[mm][c0 + v8 * 8];
                #pragma unroll
                for (int j = 0; j < 8; ++j) acc[v8 * 8 + j] += p * bf2f(u[j]);
            }
        }
        __syncthreads();  // before next chunk overwrites Ks/Vs
    }

    // ---- store A tile (bf16) ----
    {
        u16* ap = A + ((size_t)(b * N_ + n0 + r2) * D_ + c0);
        #pragma unroll
        for (int v8 = 0; v8 < 4; ++v8) {
            ushort8 o;
            #pragma unroll
            for (int j = 0; j < 8; ++j) o[j] = f2bf(acc[v8 * 8 + j]);
            *(ushort8*)(ap + v8 * 8) = o;
        }
    }
}

// ---------------------------------------------------------------------------
extern "C" void kernel_launch(void* const* d_in, const int* in_sizes, int n_in,
                              void* d_out, int out_size, void* d_ws, size_t ws_size,
                              hipStream_t stream)
{
    const float* Q  = (const float*)d_in[0];
    const float* K  = (const float*)d_in[1];
    const float* V  = (const float*)d_in[2];
    const float* Wq = (const float*)d_in[3];
    const float* bq = (const float*)d_in[4];
    const float* Wo = (const float*)d_in[5];
    const float* bo = (const float*)d_in[6];
    float* out = (float*)d_out;
    u16*   ws  = (u16*)d_ws;

    const size_t NBD = (size_t)B_ * N_ * D_;   // 4,194,304 elements
    u16* Qp = ws;
    u16* Kp = ws + NBD;
    u16* Vp = ws + 2 * NBD;
    u16* Ap = ws + 3 * NBD;                    // ws use: 4*NBD*2B = 33.5 MB (proven fit)

    const int M = B_ * N_;                     // 8192

    // 1) shared-weight projections (source bug: Wq/bq for Q, K, and V) -> bf16 ws
    dim3 gp(D_ / 128, M / 128, 3);
    proj_gemm<false, true><<<gp, dim3(256), 0, stream>>>(Q, K, V, Wq, bq, Qp, M);

    // 2) fused attention (softmax over heads), bf16 -> bf16
    dim3 ga(N_ / 16, B_);
    attn_fused<<<ga, dim3(256), 0, stream>>>(Qp, Kp, Vp, Ap);

    // 3) output projection: bf16 Ap @ fp32 Wo + bo -> fp32 d_out
    dim3 go(D_ / 128, M / 128, 1);
    proj_gemm<true, false><<<go, dim3(256), 0, stream>>>(Ap, Ap, Ap, Wo, bo, out, M);
}

// Round 3
// 540.154 us; speedup vs baseline: 5.0967x; 5.0967x over previous
//
#include <hip/hip_runtime.h>
#include <hip/hip_bf16.h>

// Problem constants (B,N,D,H = 4,2048,512,8; DK=64)
// fp32 inputs / fp32 output; bf16 intermediates in ws (33.5 MB, proven fit).
#define B_  4
#define N_  2048
#define D_  512
#define H_  8

typedef unsigned short u16;
typedef __attribute__((ext_vector_type(8))) unsigned short ushort8;
typedef __attribute__((ext_vector_type(8))) short short8;
typedef __attribute__((ext_vector_type(4))) float float4v;

__device__ __forceinline__ float bf2f(u16 u) {
    union { unsigned int i; float f; } v;
    v.i = ((unsigned int)u) << 16;
    return v.f;
}
__device__ __forceinline__ u16 f2bf(float f) {
    union { float f; unsigned int i; } v;
    v.f = f;
    unsigned int r = v.i + 0x7FFFu + ((v.i >> 16) & 1u);  // RNE
    return (u16)(r >> 16);
}

// async global->LDS, 16B/lane, dest = wave-uniform base + lane*16 (m104 rule)
__device__ __forceinline__ void gload_lds16(const void* g, void* l) {
    __builtin_amdgcn_global_load_lds(
        (const __attribute__((address_space(1))) unsigned int*)g,
        (__attribute__((address_space(3))) unsigned int*)l, 16, 0, 0);
}

// ---------------------------------------------------------------------------
// C[M,512] = X[M,512] @ W[512,512]^T(fp32) + bias(fp32)
// IN_BF16: X bf16 (ws) else fp32. OUT_BF16: C bf16 (ws) else fp32.
// z==2 with OUT_BF16: store TRANSPOSED per batch -> Vpt[b][e][n] (for attn B-frags).
// 128x128 tile, 256 threads, 8x8 micro-tile, BK=32.
// ---------------------------------------------------------------------------
template <bool IN_BF16, bool OUT_BF16>
__global__ __launch_bounds__(256) void proj_gemm(
    const void* __restrict__ X0v, const void* __restrict__ X1v,
    const void* __restrict__ X2v, const float* __restrict__ W,
    const float* __restrict__ bias, void* __restrict__ C0v, int M)
{
    __shared__ float As[32][132];
    __shared__ float Ws[32][132];

    const int t = threadIdx.x;
    const int z = blockIdx.z;
    const void* Xv = (z == 0) ? X0v : ((z == 1) ? X1v : X2v);

    const int e0 = blockIdx.x * 128;
    const int m0 = blockIdx.y * 128;
    const int tr = t >> 4;
    const int tc = t & 15;

    float acc[8][8] = {};

    for (int k0 = 0; k0 < 512; k0 += 32) {
        if (IN_BF16) {
            const u16* X = (const u16*)Xv;
            #pragma unroll
            for (int i = 0; i < 2; ++i) {
                int v    = t + 256 * i;
                int row  = v >> 2;
                int col8 = (v & 3) * 8;
                ushort8 ua = *(const ushort8*)(X + (size_t)(m0 + row) * 512 + k0 + col8);
                #pragma unroll
                for (int j = 0; j < 8; ++j) As[col8 + j][row] = bf2f(ua[j]);
            }
        } else {
            const float* X = (const float*)Xv;
            #pragma unroll
            for (int i = 0; i < 4; ++i) {
                int v   = t + 256 * i;
                int row = v >> 3;
                int c4  = (v & 7) * 4;
                float4v x = *(const float4v*)(X + (size_t)(m0 + row) * 512 + k0 + c4);
                #pragma unroll
                for (int j = 0; j < 4; ++j) As[c4 + j][row] = x[j];
            }
        }
        #pragma unroll
        for (int i = 0; i < 4; ++i) {
            int v   = t + 256 * i;
            int row = v >> 3;
            int c4  = (v & 7) * 4;
            float4v w = *(const float4v*)(W + (size_t)(e0 + row) * 512 + k0 + c4);
            #pragma unroll
            for (int j = 0; j < 4; ++j) Ws[c4 + j][row] = w[j];
        }
        __syncthreads();

        #pragma unroll 8
        for (int kk = 0; kk < 32; ++kk) {
            float4v a0 = *(const float4v*)&As[kk][tr * 8];
            float4v a1 = *(const float4v*)&As[kk][tr * 8 + 4];
            float4v b0 = *(const float4v*)&Ws[kk][tc * 8];
            float4v b1 = *(const float4v*)&Ws[kk][tc * 8 + 4];
            #pragma unroll
            for (int i = 0; i < 8; ++i) {
                float av = (i < 4) ? a0[i] : a1[i - 4];
                #pragma unroll
                for (int j = 0; j < 8; ++j) {
                    float bv = (j < 4) ? b0[j] : b1[j - 4];
                    acc[i][j] += av * bv;
                }
            }
        }
        __syncthreads();
    }

    if (OUT_BF16) {
        u16* C = (u16*)C0v + (size_t)z * (size_t)M * D_;
        if (z == 2) {
            // transposed store: Vpt[b][e][n], b = m0>>11 (tile within one batch)
            const int bb = m0 >> 11;
            const int nb = (m0 & (N_ - 1)) + tr * 8;
            #pragma unroll
            for (int j = 0; j < 8; ++j) {
                float bj = bias[e0 + tc * 8 + j];
                ushort8 o;
                #pragma unroll
                for (int i = 0; i < 8; ++i) o[i] = f2bf(acc[i][j] + bj);
                *(ushort8*)(C + ((size_t)(bb * D_ + e0 + tc * 8 + j) * N_ + nb)) = o;
            }
        } else {
            #pragma unroll
            for (int i = 0; i < 8; ++i) {
                ushort8 o;
                #pragma unroll
                for (int j = 0; j < 8; ++j)
                    o[j] = f2bf(acc[i][j] + bias[e0 + tc * 8 + j]);
                *(ushort8*)(C + (size_t)(m0 + tr * 8 + i) * 512 + e0 + tc * 8) = o;
            }
        }
    } else {
        float* C = (float*)C0v + (size_t)z * (size_t)M * D_;
        #pragma unroll
        for (int i = 0; i < 8; ++i) {
            float4v o0, o1;
            #pragma unroll
            for (int j = 0; j < 4; ++j) {
                o0[j] = acc[i][j]     + bias[e0 + tc * 8 + j];
                o1[j] = acc[i][j + 4] + bias[e0 + tc * 8 + 4 + j];
            }
            float* cp = C + (size_t)(m0 + tr * 8 + i) * 512 + e0 + tc * 8;
            *(float4v*)cp       = o0;
            *(float4v*)(cp + 4) = o1;
        }
    }
}

// ---------------------------------------------------------------------------
// MFMA attention, softmax over HEADS (reference's axis=1 bug).
// Block: 16 q-rows, 256 thr = 4 waves; wave w owns heads {2w,2w+1}.
// m-loop chunks of 16; PV every 2 chunks (k=32). grid = (N/16, B).
// Qp,Kp: [b][n][d] bf16. Vpt: [b][d][n] bf16 (pre-transposed). A: [b][n][d] bf16.
// MFMA 16x16x32 layouts (guide-verified): A[m=lane&15][k=quad*8+j],
// B[k=quad*8+j][n=lane&15], C/D[row=quad*4+reg][col=lane&15].
// ---------------------------------------------------------------------------
__global__ __launch_bounds__(256, 2) void attn_mfma(
    const u16* __restrict__ Qp, const u16* __restrict__ Kp,
    const u16* __restrict__ Vpt, u16* __restrict__ A)
{
    __shared__ u16 Ks[16][520];     // 16,640 B  (pad 520: 16B-aligned, bank-uniform)
    __shared__ u16 Vs[2][512][16];  // 32,768 B  (double-buffered m-halves)
    __shared__ u16 Ss[16][16][10];  // 5,120 B   scores [n][m][h] bf16
    __shared__ u16 Ps[8][16][32];   // 8,192 B   probs  [h][n][m32] bf16 (A-op order)
                                    // total 62,720 B -> 2 blocks/CU

    const int t  = threadIdx.x;
    const int w  = t >> 6;          // wave 0..3
    const int l  = t & 63;
    const int lane16 = l & 15;
    const int quad   = l >> 4;      // 0..3
    const int b  = blockIdx.y;
    const int n0 = blockIdx.x * 16;
    const int h0 = w * 2;

    // Q fragments for this wave's 2 heads (A-operand layout), persistent
    short8 qfrag[2][2];
    #pragma unroll
    for (int hh = 0; hh < 2; ++hh)
        #pragma unroll
        for (int dc = 0; dc < 2; ++dc)
            qfrag[hh][dc] = *(const short8*)(Qp +
                ((size_t)(b * N_ + n0 + lane16) * D_ + (h0 + hh) * 64 + dc * 32 + quad * 8));

    float4v aacc[2][4];
    #pragma unroll
    for (int hh = 0; hh < 2; ++hh)
        #pragma unroll
        for (int dt = 0; dt < 4; ++dt)
            aacc[hh][dt] = (float4v){0.f, 0.f, 0.f, 0.f};

    for (int c = 0; c < N_ / 16; ++c) {
        const int m0   = c * 16;
        const int half = c & 1;

        __syncthreads();  // prior chunk's LDS reads done before overwrite

        // ---- stage K rows (1 KiB each) and V d-blocks via global_load_lds ----
        #pragma unroll
        for (int i = 0; i < 4; ++i) {
            int row = w * 4 + i;
            gload_lds16(Kp + ((size_t)(b * N_ + m0 + row) * D_) + l * 8, &Ks[row][0]);
        }
        #pragma unroll
        for (int i = 0; i < 4; ++i) {
            int d0 = (w * 4 + i) * 32;
            gload_lds16(Vpt + ((size_t)(b * D_ + d0 + (l >> 1)) * N_ + m0 + (l & 1) * 8),
                        &Vs[half][d0][0]);
        }
        __syncthreads();  // staging complete (syncthreads drains vmcnt)

        // ---- QK^T for this wave's heads: S[16n x 16m], k=64 over 2 MFMAs ----
        #pragma unroll
        for (int hh = 0; hh < 2; ++hh) {
            float4v s = {0.f, 0.f, 0.f, 0.f};
            #pragma unroll
            for (int dc = 0; dc < 2; ++dc) {
                short8 kf = *(const short8*)(&Ks[lane16][(h0 + hh) * 64 + dc * 32 + quad * 8]);
                s = __builtin_amdgcn_mfma_f32_16x16x32_bf16(qfrag[hh][dc], kf, s, 0, 0, 0);
            }
            #pragma unroll
            for (int r = 0; r < 4; ++r)
                Ss[quad * 4 + r][lane16][h0 + hh] = f2bf(s[r] * 0.125f); // 1/sqrt(64)
        }
        __syncthreads();  // S ready

        // ---- softmax over 8 heads, one (n,m) per thread; write P (A-op order) ----
        {
            const int n = t >> 4, m = t & 15;
            float sv[8];
            #pragma unroll
            for (int h = 0; h < 8; ++h) sv[h] = bf2f(Ss[n][m][h]);
            float mx = sv[0];
            #pragma unroll
            for (int h = 1; h < 8; ++h) mx = fmaxf(mx, sv[h]);
            float sum = 0.f;
            #pragma unroll
            for (int h = 0; h < 8; ++h) { sv[h] = __expf(sv[h] - mx); sum += sv[h]; }
            float inv = 1.f / sum;
            #pragma unroll
            for (int h = 0; h < 8; ++h) Ps[h][n][half * 16 + m] = f2bf(sv[h] * inv);
        }

        // ---- PV every second chunk: k = 32 accumulated m's ----
        if (half) {
            __syncthreads();  // P (both halves) + Vs (both halves) ready
            #pragma unroll
            for (int hh = 0; hh < 2; ++hh) {
                const int h = h0 + hh;
                short8 pf = *(const short8*)(&Ps[h][lane16][quad * 8]);
                #pragma unroll
                for (int dt = 0; dt < 4; ++dt) {
                    const int d = h * 64 + dt * 16 + lane16;
                    short8 vf = *(const short8*)(&Vs[quad >> 1][d][(quad & 1) * 8]);
                    aacc[hh][dt] = __builtin_amdgcn_mfma_f32_16x16x32_bf16(pf, vf, aacc[hh][dt], 0, 0, 0);
                }
            }
        }
    }

    // ---- store combined-head A (bf16) ----
    #pragma unroll
    for (int hh = 0; hh < 2; ++hh)
        #pragma unroll
        for (int dt = 0; dt < 4; ++dt)
            #pragma unroll
            for (int r = 0; r < 4; ++r) {
                const int n = n0 + quad * 4 + r;
                const int d = (h0 + hh) * 64 + dt * 16 + lane16;
                A[(size_t)(b * N_ + n) * D_ + d] = f2bf(aacc[hh][dt][r]);
            }
}

// ---------------------------------------------------------------------------
extern "C" void kernel_launch(void* const* d_in, const int* in_sizes, int n_in,
                              void* d_out, int out_size, void* d_ws, size_t ws_size,
                              hipStream_t stream)
{
    const float* Q  = (const float*)d_in[0];
    const float* K  = (const float*)d_in[1];
    const float* V  = (const float*)d_in[2];
    const float* Wq = (const float*)d_in[3];
    const float* bq = (const float*)d_in[4];
    const float* Wo = (const float*)d_in[5];
    const float* bo = (const float*)d_in[6];
    float* out = (float*)d_out;
    u16*   ws  = (u16*)d_ws;

    const size_t NBD = (size_t)B_ * N_ * D_;   // 4,194,304
    u16* Qp  = ws;                // [b][n][d]
    u16* Kp  = ws + NBD;          // [b][n][d]
    u16* Vpt = ws + 2 * NBD;      // [b][d][n]  (transposed in proj epilogue)
    u16* Ap  = ws + 3 * NBD;      // [b][n][d]

    const int M = B_ * N_;        // 8192

    // 1) shared-weight projections (source bug: Wq/bq for Q, K, AND V)
    dim3 gp(D_ / 128, M / 128, 3);
    proj_gemm<false, true><<<gp, dim3(256), 0, stream>>>(Q, K, V, Wq, bq, Qp, M);

    // 2) MFMA attention (softmax over heads)
    dim3 ga(N_ / 16, B_);
    attn_mfma<<<ga, dim3(256), 0, stream>>>(Qp, Kp, Vpt, Ap);

    // 3) output projection: bf16 Ap @ fp32 Wo + bo -> fp32 d_out
    dim3 go(D_ / 128, M / 128, 1);
    proj_gemm<true, false><<<go, dim3(256), 0, stream>>>(Ap, Ap, Ap, Wo, bo, out, M);
}

// Round 5
// 364.983 us; speedup vs baseline: 7.5429x; 1.4799x over previous
//
#include <hip/hip_runtime.h>
#include <hip/hip_bf16.h>

// Problem constants (B,N,D,H = 4,2048,512,8; DK=64)
// fp32 inputs / fp32 output; bf16 intermediates in ws (33.5 MB, proven fit).
#define B_  4
#define N_  2048
#define D_  512
#define H_  8

typedef unsigned short u16;
typedef __attribute__((ext_vector_type(8))) unsigned short ushort8;
typedef __attribute__((ext_vector_type(4))) unsigned short us4;   // NB: 'ushort4' collides with HIP vector types
typedef __attribute__((ext_vector_type(8))) short short8;
typedef __attribute__((ext_vector_type(4))) float float4v;

__device__ __forceinline__ float bf2f(u16 u) {
    union { unsigned int i; float f; } v;
    v.i = ((unsigned int)u) << 16;
    return v.f;
}
__device__ __forceinline__ u16 f2bf(float f) {          // RNE
    union { float f; unsigned int i; } v;
    v.f = f;
    unsigned int r = v.i + 0x7FFFu + ((v.i >> 16) & 1u);
    return (u16)(r >> 16);
}
__device__ __forceinline__ u16 f2bf_fast(float f) {     // round-half-up, 2 VALU ops
    union { float f; unsigned int i; } v;
    v.f = f;
    return (u16)((v.i + 0x8000u) >> 16);
}

// async global->LDS, 16B/lane, dest = wave-uniform base + lane*16 (m104 rule)
__device__ __forceinline__ void gload_lds16(const void* g, void* l) {
    __builtin_amdgcn_global_load_lds(
        (const __attribute__((address_space(1))) unsigned int*)g,
        (__attribute__((address_space(3))) unsigned int*)l, 16, 0, 0);
}

// ---------------------------------------------------------------------------
// MFMA GEMM: C[M,512] = X[M,512] @ W[512,512]^T(fp32) + bias(fp32)
// IN_BF16: X bf16 (ws), staged via global_load_lds (As rows MUST be unpadded,
//          STRA=32). Else X fp32, VALU-convert staging (STRA=40 padded).
// OUT_BF16: C bf16 (ws); z==2 stores TRANSPOSED per batch -> Vpt[b][e][n].
// Else C fp32 (d_out).
// 128x128 tile, 256 thr = 4 waves (each 64x64 = 4x4 MFMA 16x16x32), BK=32.
// ---------------------------------------------------------------------------
template <bool IN_BF16, bool OUT_BF16, int STRA>
__global__ __launch_bounds__(256) void proj_mfma(
    const void* __restrict__ X0v, const void* __restrict__ X1v,
    const void* __restrict__ X2v, const float* __restrict__ W,
    const float* __restrict__ bias, void* __restrict__ C0v, int M)
{
    __shared__ u16 As[128][STRA];
    __shared__ u16 Bs[128][40];

    const int t = threadIdx.x;
    const int z = blockIdx.z;
    const void* Xv = (z == 0) ? X0v : ((z == 1) ? X1v : X2v);
    const int e0 = blockIdx.x * 128;
    const int m0 = blockIdx.y * 128;
    const int w = t >> 6, l = t & 63;
    const int lane16 = l & 15, quad = l >> 4;
    const int wr = (w >> 1) * 64;   // wave m-offset in tile
    const int wc = (w & 1) * 64;    // wave e-offset in tile

    float4v acc[4][4];
    #pragma unroll
    for (int i = 0; i < 4; ++i)
        #pragma unroll
        for (int j = 0; j < 4; ++j)
            acc[i][j] = (float4v){0.f, 0.f, 0.f, 0.f};

    for (int k0 = 0; k0 < 512; k0 += 32) {
        __syncthreads();   // previous iter's frag reads done before overwrite

        // ---- stage A tile: 128 rows x 32 k (bf16) ----
        if (IN_BF16) {
            const u16* X = (const u16*)Xv;
            #pragma unroll
            for (int i = 0; i < 2; ++i) {
                int r0 = w * 32 + i * 16;   // wave-uniform
                gload_lds16(X + (size_t)(m0 + r0 + (l >> 2)) * 512 + k0 + (l & 3) * 8,
                            &As[r0][0]);
            }
        } else {
            const float* X = (const float*)Xv;
            #pragma unroll
            for (int i = 0; i < 2; ++i) {
                int v   = t + 256 * i;       // 0..511
                int row = v >> 2;            // 0..127
                int c8  = (v & 3) * 8;       // 0,8,16,24
                const float* xp = X + (size_t)(m0 + row) * 512 + k0 + c8;
                float4v x0 = *(const float4v*)xp;
                float4v x1 = *(const float4v*)(xp + 4);
                ushort8 o;
                #pragma unroll
                for (int j = 0; j < 4; ++j) {
                    o[j]     = f2bf_fast(x0[j]);
                    o[j + 4] = f2bf_fast(x1[j]);
                }
                *(ushort8*)&As[row][c8] = o;
            }
        }
        // ---- stage B tile from W (always fp32) ----
        #pragma unroll
        for (int i = 0; i < 2; ++i) {
            int v   = t + 256 * i;
            int row = v >> 2;
            int c8  = (v & 3) * 8;
            const float* wp = W + (size_t)(e0 + row) * 512 + k0 + c8;
            float4v w0 = *(const float4v*)wp;
            float4v w1 = *(const float4v*)(wp + 4);
            ushort8 o;
            #pragma unroll
            for (int j = 0; j < 4; ++j) {
                o[j]     = f2bf_fast(w0[j]);
                o[j + 4] = f2bf_fast(w1[j]);
            }
            *(ushort8*)&Bs[row][c8] = o;
        }
        __syncthreads();   // staging visible (drains vmcnt before barrier)

        // ---- fragments + MFMA ----
        short8 af[4], bfr[4];
        #pragma unroll
        for (int i = 0; i < 4; ++i)
            af[i] = *(const short8*)&As[wr + i * 16 + lane16][quad * 8];
        #pragma unroll
        for (int j = 0; j < 4; ++j)
            bfr[j] = *(const short8*)&Bs[wc + j * 16 + lane16][quad * 8];
        #pragma unroll
        for (int i = 0; i < 4; ++i)
            #pragma unroll
            for (int j = 0; j < 4; ++j)
                acc[i][j] = __builtin_amdgcn_mfma_f32_16x16x32_bf16(
                    af[i], bfr[j], acc[i][j], 0, 0, 0);
    }

    // ---- epilogue: + bias; C-layout row=quad*4+r, col=lane16 per 16x16 tile ----
    float bj[4];
    #pragma unroll
    for (int j = 0; j < 4; ++j) bj[j] = bias[e0 + wc + j * 16 + lane16];

    if (OUT_BF16) {
        if (z == 2) {
            // transposed: Vpt[bb*D + e][n], 4 consecutive n per lane -> 8B stores
            u16* C = (u16*)C0v + 2 * (size_t)M * D_;
            #pragma unroll
            for (int i = 0; i < 4; ++i) {
                int mrow = m0 + wr + i * 16 + quad * 4;     // base of 4 n's
                int bb = mrow >> 11, nb = mrow & (N_ - 1);
                #pragma unroll
                for (int j = 0; j < 4; ++j) {
                    int e = e0 + wc + j * 16 + lane16;
                    us4 o;
                    #pragma unroll
                    for (int r = 0; r < 4; ++r) o[r] = f2bf(acc[i][j][r] + bj[j]);
                    *(us4*)(C + (size_t)(bb * D_ + e) * N_ + nb) = o;
                }
            }
        } else {
            u16* C = (u16*)C0v + (size_t)z * (size_t)M * D_;
            #pragma unroll
            for (int i = 0; i < 4; ++i)
                #pragma unroll
                for (int j = 0; j < 4; ++j) {
                    int e = e0 + wc + j * 16 + lane16;
                    #pragma unroll
                    for (int r = 0; r < 4; ++r) {
                        int mrow = m0 + wr + i * 16 + quad * 4 + r;
                        C[(size_t)mrow * D_ + e] = f2bf(acc[i][j][r] + bj[j]);
                    }
                }
        }
    } else {
        float* C = (float*)C0v;
        #pragma unroll
        for (int i = 0; i < 4; ++i)
            #pragma unroll
            for (int j = 0; j < 4; ++j) {
                int e = e0 + wc + j * 16 + lane16;
                #pragma unroll
                for (int r = 0; r < 4; ++r) {
                    int mrow = m0 + wr + i * 16 + quad * 4 + r;
                    C[(size_t)mrow * D_ + e] = acc[i][j][r] + bj[j];
                }
            }
    }
}

// ---------------------------------------------------------------------------
// MFMA attention, softmax over HEADS (reference's axis=1 bug).
// Block: 16 q-rows, 4 waves; wave w owns heads {2w,2w+1}. m-chunks of 16;
// PV every 2 chunks (k=32). grid = (N/16, B).
// Qp,Kp: [b][n][d] bf16. Vpt: [b][d][n] bf16. A: [b][n][d] bf16.
// ---------------------------------------------------------------------------
__global__ __launch_bounds__(256, 2) void attn_mfma(
    const u16* __restrict__ Qp, const u16* __restrict__ Kp,
    const u16* __restrict__ Vpt, u16* __restrict__ A)
{
    __shared__ u16 Ks[16][520];     // 16,640 B
    __shared__ u16 Vs[2][512][16];  // 32,768 B (double-buffered m-halves)
    __shared__ u16 Ss[16][16][8];   // 4,096 B  scores [n][m][h] bf16, h-contig
    __shared__ u16 Ps[8][16][32];   // 8,192 B  probs [h][n][m32] (A-op order)
                                    // total 61,696 B -> 2 blocks/CU

    const int t  = threadIdx.x;
    const int w  = t >> 6;
    const int l  = t & 63;
    const int lane16 = l & 15;
    const int quad   = l >> 4;
    const int b  = blockIdx.y;
    const int n0 = blockIdx.x * 16;
    const int h0 = w * 2;

    // Q fragments (A-operand layout), persistent
    short8 qfrag[2][2];
    #pragma unroll
    for (int hh = 0; hh < 2; ++hh)
        #pragma unroll
        for (int dc = 0; dc < 2; ++dc)
            qfrag[hh][dc] = *(const short8*)(Qp +
                ((size_t)(b * N_ + n0 + lane16) * D_ + (h0 + hh) * 64 + dc * 32 + quad * 8));

    float4v aacc[2][4];
    #pragma unroll
    for (int hh = 0; hh < 2; ++hh)
        #pragma unroll
        for (int dt = 0; dt < 4; ++dt)
            aacc[hh][dt] = (float4v){0.f, 0.f, 0.f, 0.f};

    for (int c = 0; c < N_ / 16; ++c) {
        const int m0   = c * 16;
        const int half = c & 1;

        __syncthreads();

        // ---- stage K rows and V d-blocks via global_load_lds ----
        #pragma unroll
        for (int i = 0; i < 4; ++i) {
            int row = w * 4 + i;
            gload_lds16(Kp + ((size_t)(b * N_ + m0 + row) * D_) + l * 8, &Ks[row][0]);
        }
        #pragma unroll
        for (int i = 0; i < 4; ++i) {
            int d0 = (w * 4 + i) * 32;
            gload_lds16(Vpt + ((size_t)(b * D_ + d0 + (l >> 1)) * N_ + m0 + (l & 1) * 8),
                        &Vs[half][d0][0]);
        }
        __syncthreads();

        // ---- QK^T: S[16n x 16m] per head, k=64 via 2 MFMAs ----
        #pragma unroll
        for (int hh = 0; hh < 2; ++hh) {
            float4v s = {0.f, 0.f, 0.f, 0.f};
            #pragma unroll
            for (int dc = 0; dc < 2; ++dc) {
                short8 kf = *(const short8*)(&Ks[lane16][(h0 + hh) * 64 + dc * 32 + quad * 8]);
                s = __builtin_amdgcn_mfma_f32_16x16x32_bf16(qfrag[hh][dc], kf, s, 0, 0, 0);
            }
            #pragma unroll
            for (int r = 0; r < 4; ++r)
                Ss[quad * 4 + r][lane16][h0 + hh] = f2bf(s[r] * 0.125f); // 1/sqrt(64)
        }
        __syncthreads();

        // ---- softmax over 8 heads; one (n,m) per thread; 1 b128 read ----
        {
            const int n = t >> 4, m = t & 15;
            ushort8 sv = *(const ushort8*)&Ss[n][m][0];
            float ex[8]; float sum = 0.f;
            #pragma unroll
            for (int h = 0; h < 8; ++h) { ex[h] = __expf(bf2f(sv[h])); sum += ex[h]; }
            float inv = 1.f / sum;
            #pragma unroll
            for (int h = 0; h < 8; ++h) Ps[h][n][half * 16 + m] = f2bf(ex[h] * inv);
        }

        // ---- PV every second chunk: k = 32 m's ----
        if (half) {
            __syncthreads();
            #pragma unroll
            for (int hh = 0; hh < 2; ++hh) {
                const int h = h0 + hh;
                short8 pf = *(const short8*)(&Ps[h][lane16][quad * 8]);
                #pragma unroll
                for (int dt = 0; dt < 4; ++dt) {
                    const int d = h * 64 + dt * 16 + lane16;
                    short8 vf = *(const short8*)(&Vs[quad >> 1][d][(quad & 1) * 8]);
                    aacc[hh][dt] = __builtin_amdgcn_mfma_f32_16x16x32_bf16(pf, vf, aacc[hh][dt], 0, 0, 0);
                }
            }
        }
    }

    // ---- store combined-head A (bf16) ----
    #pragma unroll
    for (int hh = 0; hh < 2; ++hh)
        #pragma unroll
        for (int dt = 0; dt < 4; ++dt)
            #pragma unroll
            for (int r = 0; r < 4; ++r) {
                const int n = n0 + quad * 4 + r;
                const int d = (h0 + hh) * 64 + dt * 16 + lane16;
                A[(size_t)(b * N_ + n) * D_ + d] = f2bf(aacc[hh][dt][r]);
            }
}

// ---------------------------------------------------------------------------
extern "C" void kernel_launch(void* const* d_in, const int* in_sizes, int n_in,
                              void* d_out, int out_size, void* d_ws, size_t ws_size,
                              hipStream_t stream)
{
    const float* Q  = (const float*)d_in[0];
    const float* K  = (const float*)d_in[1];
    const float* V  = (const float*)d_in[2];
    const float* Wq = (const float*)d_in[3];
    const float* bq = (const float*)d_in[4];
    const float* Wo = (const float*)d_in[5];
    const float* bo = (const float*)d_in[6];
    float* out = (float*)d_out;
    u16*   ws  = (u16*)d_ws;

    const size_t NBD = (size_t)B_ * N_ * D_;   // 4,194,304
    u16* Qp  = ws;                // [b][n][d]
    u16* Kp  = ws + NBD;          // [b][n][d]
    u16* Vpt = ws + 2 * NBD;      // [b][d][n]
    u16* Ap  = ws + 3 * NBD;      // [b][n][d]

    const int M = B_ * N_;        // 8192

    // 1) shared-weight projections (source bug: Wq/bq for Q, K, AND V) -> bf16 ws
    dim3 gp(D_ / 128, M / 128, 3);
    proj_mfma<false, true, 40><<<gp, dim3(256), 0, stream>>>(Q, K, V, Wq, bq, Qp, M);

    // 2) MFMA attention (softmax over heads)
    dim3 ga(N_ / 16, B_);
    attn_mfma<<<ga, dim3(256), 0, stream>>>(Qp, Kp, Vpt, Ap);

    // 3) output projection: bf16 Ap @ Wo^T + bo -> fp32 d_out
    dim3 go(D_ / 128, M / 128, 1);
    proj_mfma<true, false, 32><<<go, dim3(256), 0, stream>>>(Ap, Ap, Ap, Wo, bo, out, M);
}